// Round 1
// baseline (163.930 us; speedup 1.0000x reference)
//
#include <hip/hip_runtime.h>

// Volume layout [T, Z, Y, X] = [32, 64, 128, 128], fp32.
// Output: [4, T, Z, Y, X] = forward differences along x, y, z, t with zero at
// the last index of each respective axis. h = 1 for all axes.

#define DX 128
#define DY 128
#define DZ 64
#define DT 32

__global__ __launch_bounds__(256) void nabla4d_kernel(const float* __restrict__ x,
                                                      float* __restrict__ out) {
    constexpr int NX4    = DX / 4;                 // 32 quads per x-row
    constexpr int N      = DT * DZ * DY * DX;      // 33,554,432 elements
    constexpr int NQ     = N / 4;                  // 8,388,608 quads
    constexpr int SY     = DX;                     // stride to y+1
    constexpr int SZ     = DX * DY;                // stride to z+1
    constexpr int ST     = DX * DY * DZ;           // stride to t+1

    const int stride = gridDim.x * blockDim.x;
    for (int q = blockIdx.x * blockDim.x + threadIdx.x; q < NQ; q += stride) {
        const int base = q << 2;

        // decompose q -> (t, z, y, xq); all dims are powers of two
        const int xq   = q & (NX4 - 1);            // quad index within x-row
        const int rem  = q >> 5;                   // / NX4
        const int y    = rem & (DY - 1);
        const int rem2 = rem >> 7;                 // / DY
        const int z    = rem2 & (DZ - 1);
        const int t    = rem2 >> 6;                // / DZ

        const float4 v = *reinterpret_cast<const float4*>(x + base);

        // ---- gx: forward diff along x (zero at x == DX-1) ----
        float4 gx;
        gx.x = v.y - v.x;
        gx.y = v.z - v.y;
        gx.z = v.w - v.z;
        if (xq < NX4 - 1) {
            gx.w = x[base + 4] - v.w;
        } else {
            gx.w = 0.0f;
        }

        // ---- gy: forward diff along y (zero at y == DY-1) ----
        float4 gy;
        if (y < DY - 1) {
            const float4 vy = *reinterpret_cast<const float4*>(x + base + SY);
            gy.x = vy.x - v.x; gy.y = vy.y - v.y; gy.z = vy.z - v.z; gy.w = vy.w - v.w;
        } else {
            gy.x = gy.y = gy.z = gy.w = 0.0f;
        }

        // ---- gz: forward diff along z (zero at z == DZ-1) ----
        float4 gz;
        if (z < DZ - 1) {
            const float4 vz = *reinterpret_cast<const float4*>(x + base + SZ);
            gz.x = vz.x - v.x; gz.y = vz.y - v.y; gz.z = vz.z - v.z; gz.w = vz.w - v.w;
        } else {
            gz.x = gz.y = gz.z = gz.w = 0.0f;
        }

        // ---- gt: forward diff along t (zero at t == DT-1) ----
        float4 gt;
        if (t < DT - 1) {
            const float4 vt = *reinterpret_cast<const float4*>(x + base + ST);
            gt.x = vt.x - v.x; gt.y = vt.y - v.y; gt.z = vt.z - v.z; gt.w = vt.w - v.w;
        } else {
            gt.x = gt.y = gt.z = gt.w = 0.0f;
        }

        // ---- coalesced float4 stores, one per output volume ----
        *reinterpret_cast<float4*>(out + 0 * N + base) = gx;
        *reinterpret_cast<float4*>(out + 1 * N + base) = gy;
        *reinterpret_cast<float4*>(out + 2 * N + base) = gz;
        *reinterpret_cast<float4*>(out + 3 * N + base) = gt;
    }
}

extern "C" void kernel_launch(void* const* d_in, const int* in_sizes, int n_in,
                              void* d_out, int out_size, void* d_ws, size_t ws_size,
                              hipStream_t stream) {
    const float* x = (const float*)d_in[0];
    float* out = (float*)d_out;

    constexpr int N  = DT * DZ * DY * DX;
    constexpr int NQ = N / 4;
    const int block = 256;
    int grid = 2048;                       // grid-stride; 16 quads per thread
    if (grid > (NQ + block - 1) / block) grid = (NQ + block - 1) / block;

    nabla4d_kernel<<<grid, block, 0, stream>>>(x, out);
}

// Round 2
// 113.489 us; speedup vs baseline: 1.4445x; 1.4445x over previous
//
#include <hip/hip_runtime.h>

// Volume layout [T, Z, Y, X] = [32, 64, 128, 128], fp32.
// Output: [4, T, Z, Y, X] = forward differences along x, y, z, t with zero at
// the last index of each respective axis. h = 1 for all axes.
//
// Strategy: one thread per (z, y, x-quad) column, looping over t. x[t+1] is
// loaded once per iteration and reused as both the gt operand and next
// iteration's center value -> no redundant 4MiB-stride fetch. Outputs are
// written with non-temporal stores so the 512MB write stream doesn't evict
// the input from L2 (which the y/z neighbor loads rely on).

#define DX 128
#define DY 128
#define DZ 64
#define DT 32

typedef float v4f __attribute__((ext_vector_type(4)));

__global__ __launch_bounds__(256) void nabla4d_kernel(const float* __restrict__ x,
                                                      float* __restrict__ out) {
    constexpr int NXQ = DX / 4;               // 32 quads per x-row
    constexpr int N   = DT * DZ * DY * DX;    // 33,554,432 elements
    constexpr int SY  = DX;                   // stride to y+1
    constexpr int SZ  = DX * DY;              // stride to z+1
    constexpr int ST  = DX * DY * DZ;         // stride to t+1
    constexpr int NCOL = DZ * DY * NXQ;       // 262,144 columns

    const int col = blockIdx.x * blockDim.x + threadIdx.x;
    if (col >= NCOL) return;

    const int xq = col & (NXQ - 1);           // quad index within x-row
    const int y  = (col >> 5) & (DY - 1);
    const int z  = col >> 12;

    const int s = z * SZ + y * SY + (xq << 2);  // spatial offset within a t-plane

    const bool has_x = (xq < NXQ - 1);
    const bool has_y = (y  < DY - 1);
    const bool has_z = (z  < DZ - 1);

    v4f v = *reinterpret_cast<const v4f*>(x + s);   // x[t=0] at this column

    for (int t = 0; t < DT; ++t) {
        const int base = t * ST + s;

        // next t-plane value: gt operand AND next iteration's center
        v4f vn;
        const bool has_t = (t < DT - 1);
        if (has_t) {
            vn = *reinterpret_cast<const v4f*>(x + base + ST);
        } else {
            vn = (v4f)0.0f;
        }

        // ---- gx: forward diff along x (zero at x == DX-1) ----
        v4f gx;
        gx.x = v.y - v.x;
        gx.y = v.z - v.y;
        gx.z = v.w - v.z;
        gx.w = has_x ? (x[base + 4] - v.w) : 0.0f;

        // ---- gy: forward diff along y ----
        v4f gy;
        if (has_y) {
            const v4f vy = *reinterpret_cast<const v4f*>(x + base + SY);
            gy = vy - v;
        } else {
            gy = (v4f)0.0f;
        }

        // ---- gz: forward diff along z ----
        v4f gz;
        if (has_z) {
            const v4f vz = *reinterpret_cast<const v4f*>(x + base + SZ);
            gz = vz - v;
        } else {
            gz = (v4f)0.0f;
        }

        // ---- gt: forward diff along t ----
        v4f gt = has_t ? (vn - v) : (v4f)0.0f;

        // ---- non-temporal coalesced stores, one per output volume ----
        __builtin_nontemporal_store(gx, reinterpret_cast<v4f*>(out + 0 * N + base));
        __builtin_nontemporal_store(gy, reinterpret_cast<v4f*>(out + 1 * N + base));
        __builtin_nontemporal_store(gz, reinterpret_cast<v4f*>(out + 2 * N + base));
        __builtin_nontemporal_store(gt, reinterpret_cast<v4f*>(out + 3 * N + base));

        v = vn;
    }
}

extern "C" void kernel_launch(void* const* d_in, const int* in_sizes, int n_in,
                              void* d_out, int out_size, void* d_ws, size_t ws_size,
                              hipStream_t stream) {
    const float* x = (const float*)d_in[0];
    float* out = (float*)d_out;

    constexpr int NCOL = DZ * DY * (DX / 4);   // 262,144 columns
    const int block = 256;
    const int grid  = NCOL / block;            // 1024 blocks

    nabla4d_kernel<<<grid, block, 0, stream>>>(x, out);
}

// Round 3
// 106.451 us; speedup vs baseline: 1.5400x; 1.0661x over previous
//
#include <hip/hip_runtime.h>

// Volume layout [T, Z, Y, X] = [32, 64, 128, 128], fp32.
// Output: [4, T, Z, Y, X] = forward differences along x, y, z, t with zero at
// the last index of each respective axis. h = 1 for all axes.
//
// Strategy: one thread per (chunk, z, y, x-quad), each owning a 16-long
// t-segment of a column. x[t+1] is loaded once per iteration and reused as
// both the gt operand and next iteration's center value. Non-temporal stores
// keep the 512MB write stream from evicting the (L3-resident) input.
// 2 chunks -> 2048 blocks (8/CU) for more memory-level parallelism;
// unroll-4 lets the compiler batch loads ahead of uses.

#define DX 128
#define DY 128
#define DZ 64
#define DT 32

typedef float v4f __attribute__((ext_vector_type(4)));

__global__ __launch_bounds__(256) void nabla4d_kernel(const float* __restrict__ x,
                                                      float* __restrict__ out) {
    constexpr int NXQ   = DX / 4;               // 32 quads per x-row
    constexpr int N     = DT * DZ * DY * DX;    // 33,554,432 elements
    constexpr int SY    = DX;                   // stride to y+1
    constexpr int SZ    = DX * DY;              // stride to z+1
    constexpr int ST    = DX * DY * DZ;         // stride to t+1
    constexpr int NCOL  = DZ * DY * NXQ;        // 262,144 columns
    constexpr int TCHUNK = 16;                  // t-steps per thread

    const int gid   = blockIdx.x * blockDim.x + threadIdx.x;
    const int col   = gid & (NCOL - 1);
    const int chunk = gid >> 18;                // 0 or 1

    const int xq = col & (NXQ - 1);             // quad index within x-row
    const int y  = (col >> 5) & (DY - 1);
    const int z  = col >> 12;

    const int s  = z * SZ + y * SY + (xq << 2); // spatial offset within a t-plane
    const int t0 = chunk * TCHUNK;

    const bool has_x = (xq < NXQ - 1);
    const bool has_y = (y  < DY - 1);
    const bool has_z = (z  < DZ - 1);

    v4f v = *reinterpret_cast<const v4f*>(x + t0 * ST + s);  // center at t0

    #pragma unroll 4
    for (int dt = 0; dt < TCHUNK; ++dt) {
        const int t    = t0 + dt;
        const int base = t * ST + s;
        const bool has_t = (t < DT - 1);

        // next t-plane value: gt operand AND next iteration's center
        v4f vn;
        if (has_t) {
            vn = *reinterpret_cast<const v4f*>(x + base + ST);
        } else {
            vn = (v4f)0.0f;
        }

        // ---- gx: forward diff along x (zero at x == DX-1) ----
        v4f gx;
        gx.x = v.y - v.x;
        gx.y = v.z - v.y;
        gx.z = v.w - v.z;
        gx.w = has_x ? (x[base + 4] - v.w) : 0.0f;

        // ---- gy: forward diff along y ----
        v4f gy;
        if (has_y) {
            const v4f vy = *reinterpret_cast<const v4f*>(x + base + SY);
            gy = vy - v;
        } else {
            gy = (v4f)0.0f;
        }

        // ---- gz: forward diff along z ----
        v4f gz;
        if (has_z) {
            const v4f vz = *reinterpret_cast<const v4f*>(x + base + SZ);
            gz = vz - v;
        } else {
            gz = (v4f)0.0f;
        }

        // ---- gt: forward diff along t ----
        v4f gt = has_t ? (vn - v) : (v4f)0.0f;

        // ---- non-temporal coalesced stores, one per output volume ----
        __builtin_nontemporal_store(gx, reinterpret_cast<v4f*>(out + 0 * N + base));
        __builtin_nontemporal_store(gy, reinterpret_cast<v4f*>(out + 1 * N + base));
        __builtin_nontemporal_store(gz, reinterpret_cast<v4f*>(out + 2 * N + base));
        __builtin_nontemporal_store(gt, reinterpret_cast<v4f*>(out + 3 * N + base));

        v = vn;
    }
}

extern "C" void kernel_launch(void* const* d_in, const int* in_sizes, int n_in,
                              void* d_out, int out_size, void* d_ws, size_t ws_size,
                              hipStream_t stream) {
    const float* x = (const float*)d_in[0];
    float* out = (float*)d_out;

    constexpr int NCOL   = DZ * DY * (DX / 4);  // 262,144 columns
    constexpr int NCHUNK = 2;
    const int block = 256;
    const int grid  = NCOL * NCHUNK / block;    // 2048 blocks

    nabla4d_kernel<<<grid, block, 0, stream>>>(x, out);
}